// Round 1
// baseline (452.850 us; speedup 1.0000x reference)
//
#include <hip/hip_runtime.h>
#include <hip/hip_bf16.h>
#include <math.h>

// Problem constants
// B=4, T=2048, C=1024, H=16, D=64, M = B*T = 8192

typedef short bf16x8 __attribute__((ext_vector_type(8)));
typedef float f32x4 __attribute__((ext_vector_type(4)));

__device__ __forceinline__ short f2b(float f) {
    // round-to-nearest-even fp32 -> bf16
    unsigned u = __float_as_uint(f);
    u = (u + 0x7fffu + ((u >> 16) & 1u)) >> 16;
    return (short)u;
}

// ---------------------------------------------------------------- cast x
__global__ __launch_bounds__(256) void cast_x_kernel(const float* __restrict__ x,
                                                     short* __restrict__ xb, int n4) {
    int idx = blockIdx.x * 256 + threadIdx.x;
    if (idx >= n4) return;
    float4 v = ((const float4*)x)[idx];
    short4 o;
    o.x = f2b(v.x); o.y = f2b(v.y); o.z = f2b(v.z); o.w = f2b(v.w);
    ((short4*)xb)[idx] = o;
}

// ------------------------------------------- cast + transpose weights (fp32 [K][N] -> bf16 [N][K])
__global__ __launch_bounds__(256) void wtrans_kernel(const float* W0, const float* W1,
                                                     const float* W2, const float* W3,
                                                     short* O0, short* O1, short* O2, short* O3) {
    const float* W; short* O;
    switch (blockIdx.z) {
        case 0: W = W0; O = O0; break;
        case 1: W = W1; O = O1; break;
        case 2: W = W2; O = O2; break;
        default: W = W3; O = O3; break;
    }
    __shared__ __align__(16) float Ls[64 * 68];
    int tid = threadIdx.x;
    int n0 = blockIdx.x * 64, k0 = blockIdx.y * 64;
    #pragma unroll
    for (int it = 0; it < 4; ++it) {
        int c = tid + it * 256;          // 1024 float4 chunks
        int r = c >> 4, off = (c & 15) * 4;
        *(float4*)&Ls[r * 68 + off] = *(const float4*)&W[(k0 + r) * 1024 + n0 + off];
    }
    __syncthreads();
    #pragma unroll
    for (int it = 0; it < 2; ++it) {
        int c = tid + it * 256;          // 512 bf16x8 chunks
        int n = c >> 3, koff = (c & 7) * 8;
        union { short s[8]; int4 v; } u;
        #pragma unroll
        for (int k = 0; k < 8; ++k) u.s[k] = f2b(Ls[(koff + k) * 68 + n]);
        *(int4*)&O[(n0 + n) * 1024 + k0 + koff] = u.v;
    }
}

// ---------------------------------------------------------------- GEMM 128x128, BK=64
// A [M=8192][K=1024] bf16 row-major; Bt [N=1024][K=1024] bf16 (B transposed)
// MODE 0: out bf16 scattered to [B,H,T,D]; MODE 1: out fp32 row-major [M][N]
template<int MODE>
__global__ __launch_bounds__(256, 2) void gemm_kernel(const short* __restrict__ A,
                                                      const short* Bt0, const short* Bt1, const short* Bt2,
                                                      const float* b0, const float* b1, const float* b2,
                                                      void* O0, void* O1, void* O2) {
    const short* Bt; const float* bias; void* Out;
    int z = blockIdx.z;
    Bt   = (z == 0) ? Bt0 : (z == 1) ? Bt1 : Bt2;
    bias = (z == 0) ? b0  : (z == 1) ? b1  : b2;
    Out  = (z == 0) ? O0  : (z == 1) ? O1  : O2;

    __shared__ __align__(16) short As[128 * 72];
    __shared__ __align__(16) short Bs[128 * 72];

    int tid = threadIdx.x;
    int w = tid >> 6, lane = tid & 63, quad = lane >> 4, l15 = lane & 15;
    int m0 = blockIdx.x * 128, n0 = blockIdx.y * 128;
    int wm = (w >> 1) * 64, wn = (w & 1) * 64;

    f32x4 acc[4][4] = {};

    for (int kt = 0; kt < 16; ++kt) {
        int k0 = kt * 64;
        __syncthreads();
        #pragma unroll
        for (int it = 0; it < 4; ++it) {
            int c = tid + it * 256;      // 1024 chunks of 8 bf16
            int r = c >> 3, off = (c & 7) * 8;
            *(int4*)&As[r * 72 + off] = *(const int4*)&A[(m0 + r) * 1024 + k0 + off];
            *(int4*)&Bs[r * 72 + off] = *(const int4*)&Bt[(n0 + r) * 1024 + k0 + off];
        }
        __syncthreads();
        #pragma unroll
        for (int kk = 0; kk < 2; ++kk) {
            bf16x8 af[4], bf[4];
            #pragma unroll
            for (int i = 0; i < 4; ++i)
                af[i] = *(const bf16x8*)&As[(wm + i * 16 + l15) * 72 + kk * 32 + quad * 8];
            #pragma unroll
            for (int j = 0; j < 4; ++j)
                bf[j] = *(const bf16x8*)&Bs[(wn + j * 16 + l15) * 72 + kk * 32 + quad * 8];
            #pragma unroll
            for (int i = 0; i < 4; ++i)
                #pragma unroll
                for (int j = 0; j < 4; ++j)
                    acc[i][j] = __builtin_amdgcn_mfma_f32_16x16x32_bf16(af[i], bf[j], acc[i][j], 0, 0, 0);
        }
    }
    // epilogue: C/D layout col=lane&15, row=quad*4+reg  [m89/m91 verified]
    #pragma unroll
    for (int i = 0; i < 4; ++i) {
        #pragma unroll
        for (int j = 0; j < 4; ++j) {
            int gn = n0 + wn + j * 16 + l15;
            float bv = bias[gn];
            #pragma unroll
            for (int r = 0; r < 4; ++r) {
                int gm = m0 + wm + i * 16 + quad * 4 + r;
                float v = acc[i][j][r] + bv;
                if (MODE == 0) {
                    int b = gm >> 11, t = gm & 2047, h = gn >> 6, d = gn & 63;
                    ((short*)Out)[(((b * 16 + h) * 2048) + t) * 64 + d] = f2b(v);
                } else {
                    ((float*)Out)[gm * 1024 + gn] = v;
                }
            }
        }
    }
}

// ---------------------------------------------------------------- V [bh][t][d] -> Vt [bh][d][t]
__global__ __launch_bounds__(256) void vtrans_kernel(const short* __restrict__ V,
                                                     short* __restrict__ Vt) {
    __shared__ __align__(16) short Ts[64 * 72];
    int tid = threadIdx.x;
    int bh = blockIdx.y;
    int t0 = blockIdx.x * 64;
    #pragma unroll
    for (int it = 0; it < 2; ++it) {
        int c = tid + it * 256;          // 512 chunks
        int r = c >> 3, off = (c & 7) * 8;
        *(int4*)&Ts[r * 72 + off] = *(const int4*)&V[(bh * 2048 + t0 + r) * 64 + off];
    }
    __syncthreads();
    #pragma unroll
    for (int it = 0; it < 2; ++it) {
        int c = tid + it * 256;
        int d = c >> 3, toff = (c & 7) * 8;
        union { short s[8]; int4 v; } u;
        #pragma unroll
        for (int k = 0; k < 8; ++k) u.s[k] = Ts[(toff + k) * 72 + d];
        *(int4*)&Vt[(bh * 64 + d) * 2048 + t0 + toff] = u.v;
    }
}

// ---------------------------------------------------------------- flash attention
// Q,K: [bh][t][d] bf16 ; Vt: [bh][d][t] bf16 ; Y: [b*T+t][C] bf16 (heads merged)
__global__ __launch_bounds__(256, 2) void attn_kernel(const short* __restrict__ Q,
                                                      const short* __restrict__ K,
                                                      const short* __restrict__ Vt,
                                                      short* __restrict__ Y) {
    // LDS: union { K tile [128][72] (18432B) | P tile [128][136] (34816B) } + V tile [64][136] (17408B)
    __shared__ __align__(16) char smem[34816 + 17408];
    short* Ks = (short*)smem;
    short* Ps = (short*)smem;
    short* Vs = (short*)(smem + 34816);

    int tid = threadIdx.x;
    int w = tid >> 6, lane = tid & 63, quad = lane >> 4, l15 = lane & 15;
    int qi = blockIdx.x, bh = blockIdx.y;

    const short* Qh = Q + bh * 2048 * 64;
    const short* Kh = K + bh * 2048 * 64;
    const short* Vh = Vt + bh * 64 * 2048;

    // Q fragments in registers: A-layout A[m=lane&15][k=quad*8+j]  [m120 verified]
    bf16x8 qf[2][2];
    #pragma unroll
    for (int i = 0; i < 2; ++i)
        #pragma unroll
        for (int kh = 0; kh < 2; ++kh) {
            int t = qi * 128 + w * 32 + i * 16 + l15;
            qf[i][kh] = *(const bf16x8*)&Qh[t * 64 + kh * 32 + quad * 8];
        }

    f32x4 o[2][4] = {};
    float mrow[2][4], lrow[2][4];
    #pragma unroll
    for (int i = 0; i < 2; ++i)
        #pragma unroll
        for (int r = 0; r < 4; ++r) { mrow[i][r] = -INFINITY; lrow[i][r] = 0.f; }

    const float sc = 0.125f;  // 1/sqrt(64)

    for (int si = 0; si <= qi; ++si) {
        __syncthreads();  // prior tile's PV done before restaging
        #pragma unroll
        for (int it = 0; it < 4; ++it) {
            int c = tid + it * 256;      // K tile: 1024 chunks of 8
            int r = c >> 3, off = (c & 7) * 8;
            *(int4*)&Ks[r * 72 + off] = *(const int4*)&Kh[(si * 128 + r) * 64 + off];
        }
        #pragma unroll
        for (int it = 0; it < 4; ++it) {
            int c = tid + it * 256;      // V tile: 64 d-rows x 16 chunks
            int d = c >> 4, off = (c & 15) * 8;
            *(int4*)&Vs[d * 136 + off] = *(const int4*)&Vh[d * 2048 + si * 128 + off];
        }
        __syncthreads();

        // S = Q K^T : per wave 2 m-tiles x 8 n-tiles
        f32x4 s[2][8];
        #pragma unroll
        for (int j = 0; j < 8; ++j) {
            bf16x8 kf0 = *(const bf16x8*)&Ks[(j * 16 + l15) * 72 + 0  + quad * 8];
            bf16x8 kf1 = *(const bf16x8*)&Ks[(j * 16 + l15) * 72 + 32 + quad * 8];
            #pragma unroll
            for (int i = 0; i < 2; ++i) {
                f32x4 a = {0.f, 0.f, 0.f, 0.f};
                a = __builtin_amdgcn_mfma_f32_16x16x32_bf16(qf[i][0], kf0, a, 0, 0, 0);
                a = __builtin_amdgcn_mfma_f32_16x16x32_bf16(qf[i][1], kf1, a, 0, 0, 0);
                s[i][j] = a;
            }
        }
        __syncthreads();  // everyone done reading Ks before Ps (aliased) is written

        bool diag = (si == qi);
        int s0 = si * 128;
        #pragma unroll
        for (int i = 0; i < 2; ++i) {
            #pragma unroll
            for (int r = 0; r < 4; ++r) {
                int tg = qi * 128 + w * 32 + i * 16 + quad * 4 + r;
                float vals[8];
                float mx = -INFINITY;
                #pragma unroll
                for (int j = 0; j < 8; ++j) {
                    float v = s[i][j][r] * sc;
                    if (diag && (s0 + j * 16 + l15 > tg)) v = -INFINITY;
                    vals[j] = v;
                    mx = fmaxf(mx, v);
                }
                #pragma unroll
                for (int off = 1; off < 16; off <<= 1)
                    mx = fmaxf(mx, __shfl_xor(mx, off));
                float mold = mrow[i][r];
                float mnew = fmaxf(mold, mx);
                float alpha = __expf(mold - mnew);   // first tile: exp(-inf)=0
                int prow = (w * 32 + i * 16 + quad * 4 + r) * 136;
                float rsum = 0.f;
                #pragma unroll
                for (int j = 0; j < 8; ++j) {
                    float p = __expf(vals[j] - mnew);
                    rsum += p;
                    Ps[prow + j * 16 + l15] = f2b(p);
                }
                #pragma unroll
                for (int off = 1; off < 16; off <<= 1)
                    rsum += __shfl_xor(rsum, off);
                mrow[i][r] = mnew;
                lrow[i][r] = lrow[i][r] * alpha + rsum;
                #pragma unroll
                for (int jd = 0; jd < 4; ++jd) o[i][jd][r] *= alpha;
            }
        }
        __syncthreads();  // P visible (safety; each wave reads only its own rows)

        // O += P V : A = P (A-layout from LDS), B = V via Vt tile
        #pragma unroll
        for (int ks = 0; ks < 4; ++ks) {
            bf16x8 pf[2];
            #pragma unroll
            for (int i = 0; i < 2; ++i)
                pf[i] = *(const bf16x8*)&Ps[(w * 32 + i * 16 + l15) * 136 + ks * 32 + quad * 8];
            #pragma unroll
            for (int jd = 0; jd < 4; ++jd) {
                bf16x8 vf = *(const bf16x8*)&Vs[(jd * 16 + l15) * 136 + ks * 32 + quad * 8];
                #pragma unroll
                for (int i = 0; i < 2; ++i)
                    o[i][jd] = __builtin_amdgcn_mfma_f32_16x16x32_bf16(pf[i], vf, o[i][jd], 0, 0, 0);
            }
        }
    }

    int b = bh >> 4, h = bh & 15;
    #pragma unroll
    for (int i = 0; i < 2; ++i)
        #pragma unroll
        for (int jd = 0; jd < 4; ++jd)
            #pragma unroll
            for (int r = 0; r < 4; ++r) {
                int t = qi * 128 + w * 32 + i * 16 + quad * 4 + r;
                float v = o[i][jd][r] / lrow[i][r];
                Y[(b * 2048 + t) * 1024 + h * 64 + jd * 16 + l15] = f2b(v);
            }
}

// ----------------------------------------------------------------
extern "C" void kernel_launch(void* const* d_in, const int* in_sizes, int n_in,
                              void* d_out, int out_size, void* d_ws, size_t ws_size,
                              hipStream_t stream) {
    const float* x  = (const float*)d_in[0];
    const float* Wk = (const float*)d_in[1];
    const float* bk = (const float*)d_in[2];
    const float* Wq = (const float*)d_in[3];
    const float* bq = (const float*)d_in[4];
    const float* Wv = (const float*)d_in[5];
    const float* bv = (const float*)d_in[6];
    const float* Wp = (const float*)d_in[7];
    const float* bp = (const float*)d_in[8];

    char* ws = (char*)d_ws;
    short* xb  = (short*)(ws + 0);          // 16 MB  x bf16 [8192][1024]
    short* Wqt = (short*)(ws + 16777216);   // 2 MB each, bf16 [N][K]
    short* Wkt = (short*)(ws + 18874368);
    short* Wvt = (short*)(ws + 20971520);
    short* Wpt = (short*)(ws + 23068672);
    short* Qb  = (short*)(ws + 25165824);   // 16 MB [B,H,T,D]
    short* Kb  = (short*)(ws + 41943040);   // 16 MB [B,H,T,D]
    short* Vb  = (short*)(ws + 58720256);   // 16 MB [B,H,T,D]
    short* Vtb = (short*)(ws + 75497472);   // 16 MB [B,H,D,T]
    short* Yb  = (short*)(ws + 92274688);   // 16 MB [B*T][C]

    cast_x_kernel<<<8192, 256, 0, stream>>>(x, xb, 2097152);
    wtrans_kernel<<<dim3(16, 16, 4), 256, 0, stream>>>(Wq, Wk, Wv, Wp, Wqt, Wkt, Wvt, Wpt);
    gemm_kernel<0><<<dim3(64, 8, 3), 256, 0, stream>>>(xb, Wqt, Wkt, Wvt, bq, bk, bv,
                                                       (void*)Qb, (void*)Kb, (void*)Vb);
    vtrans_kernel<<<dim3(32, 64), 256, 0, stream>>>(Vb, Vtb);
    attn_kernel<<<dim3(16, 64), 256, 0, stream>>>(Qb, Kb, Vtb, Yb);
    gemm_kernel<1><<<dim3(64, 8, 1), 256, 0, stream>>>(Yb, Wpt, nullptr, nullptr,
                                                       bp, nullptr, nullptr,
                                                       (void*)d_out, nullptr, nullptr);
}

// Round 2
// 287.690 us; speedup vs baseline: 1.5741x; 1.5741x over previous
//
#include <hip/hip_runtime.h>
#include <hip/hip_bf16.h>
#include <math.h>

// B=4, T=2048, C=1024, H=16, D=64, M = B*T = 8192

typedef short bf16x8 __attribute__((ext_vector_type(8)));
typedef float f32x4 __attribute__((ext_vector_type(4)));

__device__ __forceinline__ short f2b(float f) {
    unsigned u = __float_as_uint(f);
    u = (u + 0x7fffu + ((u >> 16) & 1u)) >> 16;
    return (short)u;
}

// ---------------------------------------------------------------- cast x
__global__ __launch_bounds__(256) void cast_x_kernel(const float* __restrict__ x,
                                                     short* __restrict__ xb, int n4) {
    int idx = blockIdx.x * 256 + threadIdx.x;
    if (idx >= n4) return;
    float4 v = ((const float4*)x)[idx];
    short4 o;
    o.x = f2b(v.x); o.y = f2b(v.y); o.z = f2b(v.z); o.w = f2b(v.w);
    ((short4*)xb)[idx] = o;
}

// ------------------------------------------- cast + transpose weights (fp32 [K][N] -> bf16 [N][K])
__global__ __launch_bounds__(256) void wtrans_kernel(const float* W0, const float* W1,
                                                     const float* W2, const float* W3,
                                                     short* O0, short* O1, short* O2, short* O3) {
    const float* W; short* O;
    switch (blockIdx.z) {
        case 0: W = W0; O = O0; break;
        case 1: W = W1; O = O1; break;
        case 2: W = W2; O = O2; break;
        default: W = W3; O = O3; break;
    }
    __shared__ __align__(16) float Ls[64 * 68];
    int tid = threadIdx.x;
    int n0 = blockIdx.x * 64, k0 = blockIdx.y * 64;
    #pragma unroll
    for (int it = 0; it < 4; ++it) {
        int c = tid + it * 256;
        int r = c >> 4, off = (c & 15) * 4;
        *(float4*)&Ls[r * 68 + off] = *(const float4*)&W[(k0 + r) * 1024 + n0 + off];
    }
    __syncthreads();
    #pragma unroll
    for (int it = 0; it < 2; ++it) {
        int c = tid + it * 256;
        int n = c >> 3, koff = (c & 7) * 8;
        union { short s[8]; int4 v; } u;
        #pragma unroll
        for (int k = 0; k < 8; ++k) u.s[k] = f2b(Ls[(koff + k) * 68 + n]);
        *(int4*)&O[(n0 + n) * 1024 + k0 + koff] = u.v;
    }
}

// ---------------------------------------------------------------- GEMM 128x128, BK=64 (m97 structure)
// A [M][1024] bf16 row-major; Bt [N][1024] bf16 (B transposed)
// MODE 0: out bf16 scattered to [B,H,T,D], scaled; MODE 1: out fp32 row-major [M][1024]
template<int MODE>
__global__ __launch_bounds__(256) void gemm_kernel(const short* __restrict__ A,
                                                   const short* Bt0, const short* Bt1, const short* Bt2,
                                                   const float* b0, const float* b1, const float* b2,
                                                   float s0, float s1, float s2,
                                                   void* O0, void* O1, void* O2) {
    int z = blockIdx.z;
    const short* Bt   = (z == 0) ? Bt0 : (z == 1) ? Bt1 : Bt2;
    const float* bias = (z == 0) ? b0  : (z == 1) ? b1  : b2;
    float scl         = (z == 0) ? s0  : (z == 1) ? s1  : s2;
    void* Out         = (z == 0) ? O0  : (z == 1) ? O1  : O2;

    __shared__ __align__(16) short As[128 * 64];   // unpadded: global_load_lds needs lane-contiguous
    __shared__ __align__(16) short Bs[128 * 64];

    int tid = threadIdx.x;
    int w = tid >> 6, lane = tid & 63, quad = lane >> 4, l15 = lane & 15;
    int m0 = blockIdx.x * 128, n0 = blockIdx.y * 128;
    int wm = (w >> 1) * 64, wn = (w & 1) * 64;
    int lrow = lane >> 3, lcol = (lane & 7) * 8;   // 8 rows x 128B per wave-instr

    f32x4 acc[4][4] = {};

    for (int kt = 0; kt < 16; ++kt) {
        int k0 = kt * 64;
        __syncthreads();
        #pragma unroll
        for (int it = 0; it < 4; ++it) {
            int r0 = it * 32 + w * 8;
            __builtin_amdgcn_global_load_lds(
                (const __attribute__((address_space(1))) unsigned int*)&A[(m0 + r0 + lrow) * 1024 + k0 + lcol],
                (__attribute__((address_space(3))) unsigned int*)&As[r0 * 64], 16, 0, 0);
            __builtin_amdgcn_global_load_lds(
                (const __attribute__((address_space(1))) unsigned int*)&Bt[(n0 + r0 + lrow) * 1024 + k0 + lcol],
                (__attribute__((address_space(3))) unsigned int*)&Bs[r0 * 64], 16, 0, 0);
        }
        __syncthreads();
        #pragma unroll
        for (int kk = 0; kk < 2; ++kk) {
            bf16x8 af[4], bf[4];
            #pragma unroll
            for (int i = 0; i < 4; ++i)
                af[i] = *(const bf16x8*)&As[(wm + i * 16 + l15) * 64 + kk * 32 + quad * 8];
            #pragma unroll
            for (int j = 0; j < 4; ++j)
                bf[j] = *(const bf16x8*)&Bs[(wn + j * 16 + l15) * 64 + kk * 32 + quad * 8];
            #pragma unroll
            for (int i = 0; i < 4; ++i)
                #pragma unroll
                for (int j = 0; j < 4; ++j)
                    acc[i][j] = __builtin_amdgcn_mfma_f32_16x16x32_bf16(af[i], bf[j], acc[i][j], 0, 0, 0);
        }
    }
    #pragma unroll
    for (int i = 0; i < 4; ++i) {
        #pragma unroll
        for (int j = 0; j < 4; ++j) {
            int gn = n0 + wn + j * 16 + l15;
            float bv = bias[gn];
            #pragma unroll
            for (int r = 0; r < 4; ++r) {
                int gm = m0 + wm + i * 16 + quad * 4 + r;
                float v = (acc[i][j][r] + bv) * scl;
                if (MODE == 0) {
                    int b = gm >> 11, t = gm & 2047, h = gn >> 6, d = gn & 63;
                    ((short*)Out)[(((b * 16 + h) * 2048) + t) * 64 + d] = f2b(v);
                } else {
                    ((float*)Out)[gm * 1024 + gn] = v;
                }
            }
        }
    }
}

// ---------------------------------------------------------------- V [bh][t][d] -> Vt [bh][d][t]
__global__ __launch_bounds__(256) void vtrans_kernel(const short* __restrict__ V,
                                                     short* __restrict__ Vt) {
    __shared__ __align__(16) short Ts[64 * 72];
    int tid = threadIdx.x;
    int bh = blockIdx.y;
    int t0 = blockIdx.x * 64;
    #pragma unroll
    for (int it = 0; it < 2; ++it) {
        int c = tid + it * 256;
        int r = c >> 3, off = (c & 7) * 8;
        *(int4*)&Ts[r * 72 + off] = *(const int4*)&V[(bh * 2048 + t0 + r) * 64 + off];
    }
    __syncthreads();
    #pragma unroll
    for (int it = 0; it < 2; ++it) {
        int c = tid + it * 256;
        int d = c >> 3, toff = (c & 7) * 8;
        union { short s[8]; int4 v; } u;
        #pragma unroll
        for (int k = 0; k < 8; ++k) u.s[k] = Ts[(toff + k) * 72 + d];
        *(int4*)&Vt[(bh * 64 + d) * 2048 + t0 + toff] = u.v;
    }
}

// ---------------------------------------------------------------- flash attention, S^T formulation
// Q,K: [bh][t][d] bf16 (Q pre-scaled by 1/sqrt(D)); Vt: [bh][d][t] bf16 ; Y: [b*T+t][C] bf16
// S^T = K Q^T via mfma(A=K, B=Q): C-layout col=l15=q, row=quad*4+r=s  -> per-lane softmax (q fixed per lane)
// O^T = V^T P^T via mfma(A=V^T, B=P^T): P^T B-frag built in-register via cross-quad shuffles
__global__ __launch_bounds__(256, 3) void attn_kernel(const short* __restrict__ Q,
                                                      const short* __restrict__ K,
                                                      const short* __restrict__ Vt,
                                                      short* __restrict__ Y) {
    __shared__ __align__(16) short Ks[128 * 72];   // 18432 B
    __shared__ __align__(16) short Vs[64 * 136];   // 17408 B  (total 35840 -> 4 blocks/CU by LDS)

    int tid = threadIdx.x;
    int w = tid >> 6, lane = tid & 63, quad = lane >> 4, l15 = lane & 15;
    int idx = blockIdx.x;
    int qi = 15 - (idx >> 6);   // longest blocks dispatched first
    int bh = idx & 63;

    const short* Qh = Q + bh * 2048 * 64;
    const short* Kh = K + bh * 2048 * 64;
    const short* Vh = Vt + bh * 64 * 2048;

    // Q fragments (B-operand layout: lane l15 = q, k = quad*8+j)
    bf16x8 qf[2][2];
    #pragma unroll
    for (int i = 0; i < 2; ++i)
        #pragma unroll
        for (int kh = 0; kh < 2; ++kh) {
            int t = qi * 128 + w * 32 + i * 16 + l15;
            qf[i][kh] = *(const bf16x8*)&Qh[t * 64 + kh * 32 + quad * 8];
        }

    f32x4 o[2][4] = {};                  // O^T: col=l15=q, row=quad*4+r = d-within-16block (mt)
    float mrow[2] = {-INFINITY, -INFINITY};
    float lrow[2] = {0.f, 0.f};

    int sA = l15 | ((lane & 16) << 1);   // source lane quad' = 2*(quad&1)
    int sB = sA | 16;
    bool hiq = (lane & 32) != 0;         // quad>>1 selects j' = 2ks+1

    for (int si = 0; si <= qi; ++si) {
        __syncthreads();
        #pragma unroll
        for (int it = 0; it < 4; ++it) {
            int c = tid + it * 256;
            int r = c >> 3, off = (c & 7) * 8;
            *(int4*)&Ks[r * 72 + off] = *(const int4*)&Kh[(si * 128 + r) * 64 + off];
        }
        #pragma unroll
        for (int it = 0; it < 4; ++it) {
            int c = tid + it * 256;
            int d = c >> 4, off = (c & 15) * 8;
            *(int4*)&Vs[d * 136 + off] = *(const int4*)&Vh[d * 2048 + si * 128 + off];
        }
        __syncthreads();

        // S^T = K Q^T : 8 s-tiles x 2 q-tiles per wave
        f32x4 s[2][8];
        #pragma unroll
        for (int j = 0; j < 8; ++j) {
            bf16x8 kf0 = *(const bf16x8*)&Ks[(j * 16 + l15) * 72 + quad * 8];
            bf16x8 kf1 = *(const bf16x8*)&Ks[(j * 16 + l15) * 72 + 32 + quad * 8];
            #pragma unroll
            for (int i = 0; i < 2; ++i) {
                f32x4 a = {};
                a = __builtin_amdgcn_mfma_f32_16x16x32_bf16(kf0, qf[i][0], a, 0, 0, 0);
                a = __builtin_amdgcn_mfma_f32_16x16x32_bf16(kf1, qf[i][1], a, 0, 0, 0);
                s[i][j] = a;
            }
        }

        bool diag = (si == qi);
        unsigned pk[2][8][2];   // bf16-pair packed P^T: lane owns q=l15(+16i), s=16j+4quad+{0..3}
        #pragma unroll
        for (int i = 0; i < 2; ++i) {
            if (diag) {
                int qrel = w * 32 + i * 16 + l15;
                #pragma unroll
                for (int j = 0; j < 8; ++j)
                    #pragma unroll
                    for (int r = 0; r < 4; ++r)
                        if (j * 16 + quad * 4 + r > qrel) s[i][j][r] = -1e30f;
            }
            float mx = -INFINITY;
            #pragma unroll
            for (int j = 0; j < 8; ++j)
                mx = fmaxf(mx, fmaxf(fmaxf(s[i][j][0], s[i][j][1]), fmaxf(s[i][j][2], s[i][j][3])));
            mx = fmaxf(mx, __shfl_xor(mx, 16));
            mx = fmaxf(mx, __shfl_xor(mx, 32));
            float mnew = fmaxf(mrow[i], mx);
            float alpha = __expf(mrow[i] - mnew);
            float rsum = 0.f;
            #pragma unroll
            for (int j = 0; j < 8; ++j) {
                float p0 = __expf(s[i][j][0] - mnew);
                float p1 = __expf(s[i][j][1] - mnew);
                float p2 = __expf(s[i][j][2] - mnew);
                float p3 = __expf(s[i][j][3] - mnew);
                rsum += (p0 + p1) + (p2 + p3);
                __hip_bfloat162 h0 = __float22bfloat162_rn(make_float2(p0, p1));
                __hip_bfloat162 h1 = __float22bfloat162_rn(make_float2(p2, p3));
                union { __hip_bfloat162 h; unsigned u; } c0, c1;
                c0.h = h0; c1.h = h1;
                pk[i][j][0] = c0.u;
                pk[i][j][1] = c1.u;
            }
            rsum += __shfl_xor(rsum, 16);
            rsum += __shfl_xor(rsum, 32);
            mrow[i] = mnew;
            lrow[i] = lrow[i] * alpha + rsum;
            #pragma unroll
            for (int mt = 0; mt < 4; ++mt) o[i][mt] *= alpha;
        }

        // O^T += V^T P^T
        #pragma unroll
        for (int ks = 0; ks < 4; ++ks) {
            bf16x8 vf[4];
            #pragma unroll
            for (int mt = 0; mt < 4; ++mt)
                vf[mt] = *(const bf16x8*)&Vs[(mt * 16 + l15) * 136 + ks * 32 + quad * 8];
            #pragma unroll
            for (int i = 0; i < 2; ++i) {
                // B-frag: lane needs s = 32ks + 8*quad + jj, jj=0..7, from lanes
                // (l15, quad'=2(quad&1)+{0,1}) at j' = 2ks + (quad>>1)   [verified by element trace]
                unsigned a0 = __shfl(pk[i][2 * ks][0], sA);
                unsigned a1 = __shfl(pk[i][2 * ks][1], sA);
                unsigned a2 = __shfl(pk[i][2 * ks][0], sB);
                unsigned a3 = __shfl(pk[i][2 * ks][1], sB);
                unsigned b0 = __shfl(pk[i][2 * ks + 1][0], sA);
                unsigned b1 = __shfl(pk[i][2 * ks + 1][1], sA);
                unsigned b2 = __shfl(pk[i][2 * ks + 1][0], sB);
                unsigned b3 = __shfl(pk[i][2 * ks + 1][1], sB);
                union { unsigned u[4]; bf16x8 v; } pf;
                pf.u[0] = hiq ? b0 : a0;
                pf.u[1] = hiq ? b1 : a1;
                pf.u[2] = hiq ? b2 : a2;
                pf.u[3] = hiq ? b3 : a3;
                #pragma unroll
                for (int mt = 0; mt < 4; ++mt)
                    o[i][mt] = __builtin_amdgcn_mfma_f32_16x16x32_bf16(vf[mt], pf.v, o[i][mt], 0, 0, 0);
            }
        }
    }

    int b = bh >> 4, h = bh & 15;
    #pragma unroll
    for (int i = 0; i < 2; ++i) {
        float rinv = 1.0f / lrow[i];
        int q = qi * 128 + w * 32 + i * 16 + l15;
        short* yrow = &Y[(b * 2048 + q) * 1024 + h * 64];
        #pragma unroll
        for (int mt = 0; mt < 4; ++mt) {
            short4 s4;
            s4.x = f2b(o[i][mt][0] * rinv);
            s4.y = f2b(o[i][mt][1] * rinv);
            s4.z = f2b(o[i][mt][2] * rinv);
            s4.w = f2b(o[i][mt][3] * rinv);
            *(short4*)&yrow[mt * 16 + quad * 4] = s4;   // d = mt*16 + quad*4 + r
        }
    }
}

// ----------------------------------------------------------------
extern "C" void kernel_launch(void* const* d_in, const int* in_sizes, int n_in,
                              void* d_out, int out_size, void* d_ws, size_t ws_size,
                              hipStream_t stream) {
    const float* x  = (const float*)d_in[0];
    const float* Wk = (const float*)d_in[1];
    const float* bk = (const float*)d_in[2];
    const float* Wq = (const float*)d_in[3];
    const float* bq = (const float*)d_in[4];
    const float* Wv = (const float*)d_in[5];
    const float* bv = (const float*)d_in[6];
    const float* Wp = (const float*)d_in[7];
    const float* bp = (const float*)d_in[8];

    char* ws = (char*)d_ws;
    short* xb  = (short*)(ws + 0);          // 16 MB  x bf16 [8192][1024]
    short* Wqt = (short*)(ws + 16777216);   // 2 MB each, bf16 [N][K]
    short* Wkt = (short*)(ws + 18874368);
    short* Wvt = (short*)(ws + 20971520);
    short* Wpt = (short*)(ws + 23068672);
    short* Qb  = (short*)(ws + 25165824);   // 16 MB [B,H,T,D] (pre-scaled by 0.125)
    short* Kb  = (short*)(ws + 41943040);   // 16 MB [B,H,T,D]
    short* Vb  = (short*)(ws + 58720256);   // 16 MB [B,H,T,D]
    short* Vtb = (short*)(ws + 75497472);   // 16 MB [B,H,D,T]
    short* Yb  = (short*)(ws + 92274688);   // 16 MB [B*T][C]

    cast_x_kernel<<<8192, 256, 0, stream>>>(x, xb, 2097152);
    wtrans_kernel<<<dim3(16, 16, 4), 256, 0, stream>>>(Wq, Wk, Wv, Wp, Wqt, Wkt, Wvt, Wpt);
    gemm_kernel<0><<<dim3(64, 8, 3), 256, 0, stream>>>(xb, Wqt, Wkt, Wvt, bq, bk, bv,
                                                       0.125f, 1.0f, 1.0f,
                                                       (void*)Qb, (void*)Kb, (void*)Vb);
    vtrans_kernel<<<dim3(32, 64), 256, 0, stream>>>(Vb, Vtb);
    attn_kernel<<<1024, 256, 0, stream>>>(Qb, Kb, Vtb, Yb);
    gemm_kernel<1><<<dim3(64, 8, 1), 256, 0, stream>>>(Yb, Wpt, nullptr, nullptr,
                                                       bp, nullptr, nullptr,
                                                       1.0f, 1.0f, 1.0f,
                                                       (void*)d_out, nullptr, nullptr);
}